// Round 4
// baseline (69.594 us; speedup 1.0000x reference)
//
#include <hip/hip_runtime.h>
#include <cmath>

#define IH 128
#define IW 128
#define NL 256          // strokes per batch image
#define NB 4            // batch
#define NS (NB * NL)    // 1024 strokes total
#define BSZ 512         // brush resolution

// Bilinear tap exactly like reference: load clipped, zero if out of range.
__device__ __forceinline__ float bil_tap(const float* __restrict__ br, int ix, int iy) {
    int cx = min(max(ix, 0), BSZ - 1);
    int cy = min(max(iy, 0), BSZ - 1);
    float v = br[cy * BSZ + cx];
    bool ok = ((unsigned)ix < (unsigned)BSZ) && ((unsigned)iy < (unsigned)BSZ);
    return ok ? v : 0.0f;
}

// ROUND-4 PROBE (resubmit of round 3 — that round died on container
// acquisition, not on the kernel). Kernel body identical to round 2
// (verified-correct, PASSED). The launcher issues it TWICE back-to-back.
// The kernel is a pure function of (brushes, params) and writes every
// output pixel exactly once per launch, so the duplicate launch is
// idempotent. Purpose: dur_us(probe) - 62.2us == one render duration.
// Pre-committed read: <=66us -> render ~2us, floor is harness-fixed,
// declare ROOFLINE; >=75us -> render ~21us, attack scan/prep next.
__global__ __launch_bounds__(256) void render_strokes(
    const float* __restrict__ brushes,  // (2,1,512,512)
    const float* __restrict__ params,   // (4,256,8)
    float* __restrict__ out)            // (4,3,128,128)
{
    __shared__ float sp[6 * NL];        // [k][stroke], k=0..5 warp rows
    __shared__ float sc[3 * NL];        // [ch][stroke] colors
    __shared__ int   sbo[NL];           // brush base offset (0 or BSZ*BSZ)

    const int t  = threadIdx.x;
    const int b  = blockIdx.x >> 9;     // 512 blocks per batch (32 px/block)
    const int sb = b * NL;

    // ---- fused warp prep: stroke sb+t -> LDS (exact ref rounding) ----
    {
        const float* __restrict__ p = params + (size_t)(sb + t) * 8;
        float x0 = p[0], y0 = p[1], w = p[2], h = p[3], th = p[4];
        float c5 = p[5], c6 = p[6], c7 = p[7];
        float ang = __fmul_rn(3.14159265358979323846f, th);
        double ds, dc;
        sincos((double)ang, &ds, &dc);  // correctly-rounded f32 after cast
        float sin_t = (float)ds;
        float cos_t = (float)dc;
        float a_x = __fsub_rn(1.0f, __fmul_rn(2.0f, x0));
        float a_y = __fsub_rn(1.0f, __fmul_rn(2.0f, y0));
        // H==W==128 -> the H/W aspect factors are exactly 1.0
        sp[0 * NL + t] = __fdiv_rn(cos_t, w);
        sp[1 * NL + t] = __fdiv_rn(sin_t, w);
        sp[2 * NL + t] = __fadd_rn(__fdiv_rn(__fmul_rn(a_x, cos_t), w),
                                   __fdiv_rn(__fmul_rn(a_y, sin_t), w));
        sp[3 * NL + t] = __fdiv_rn(-sin_t, h);
        sp[4 * NL + t] = __fdiv_rn(cos_t, h);
        sp[5 * NL + t] = __fsub_rn(__fdiv_rn(__fmul_rn(a_y, cos_t), h),
                                   __fdiv_rn(__fmul_rn(a_x, sin_t), h));
        sc[0 * NL + t] = c5;
        sc[1 * NL + t] = c6;
        sc[2 * NL + t] = c7;
        sbo[t] = (h > w) ? 0 : BSZ * BSZ;   // idx=where(h>w,0,1)
    }
    __syncthreads();

    const int lane = t & 63;
    const int wid  = t >> 6;
    const int wave = blockIdx.x * 4 + wid;      // 0..8191
    const int g    = lane >> 3;                 // pixel group 0..7
    const int j    = lane & 7;                  // stroke sub-index 0..7
    const int P    = wave * 8 + g;              // global pixel id 0..65535
    const int pix  = P & 16383;
    const int py   = pix >> 7;
    const int px   = pix & 127;

    // per-pixel constants (uniform within each 8-lane group)
    float xs1, ys1, xlo, xhi, ylo, yhi;
    {
        float xs[3], ys[3];
#pragma unroll
        for (int d = 0; d < 3; ++d) {
            int qx = px + d - 1, qy = py + d - 1;
            xs[d] = (2.0f * (float)qx + 1.0f) / 128.0f - 1.0f;   // exact in f32
            ys[d] = (2.0f * (float)qy + 1.0f) / 128.0f - 1.0f;
        }
        xs1 = xs[1]; ys1 = ys[1];
        // inactive erosion taps duplicate the (always-active) center coord;
        // result stays monotone, so only the endpoints matter.
        xlo = (px - 1 >= 0) ? xs[0] : xs1;
        xhi = (px + 1 < IW) ? xs[2] : xs1;
        ylo = (py - 1 >= 0) ? ys[0] : ys1;
        yhi = (py + 1 < IH) ? ys[2] : ys1;
    }

    const size_t pixo = (size_t)py * IW + px;
    const size_t img  = (size_t)b * 3 * IH * IW;
    bool gfound = false;
    bool winner = false;
    int  wls    = 0;

    for (int c = 0; c < 32; ++c) {
        bool cov = false;
        int ls = 0;

        if (!gfound) {
            ls = (NL - 8 - 8 * c) + j;          // local stroke id, chunk from top
            const float w00 = sp[0 * NL + ls];
            const float w01 = sp[1 * NL + ls];
            const float w02 = sp[2 * NL + ls];
            const float w10 = sp[3 * NL + ls];
            const float w11 = sp[4 * NL + ls];
            const float w12 = sp[5 * NL + ls];

            // endpoint selection by coefficient sign (monotone xse/yse proof)
            float xa = (w00 >= 0.0f) ? xlo : xhi;   // minimizes x*w00
            float xb = (w00 >= 0.0f) ? xhi : xlo;   // maximizes x*w00
            float ya = (w01 >= 0.0f) ? ylo : yhi;
            float yb = (w01 >= 0.0f) ? yhi : ylo;
            float xc = (w10 >= 0.0f) ? xlo : xhi;
            float xd = (w10 >= 0.0f) ? xhi : xlo;
            float ye = (w11 >= 0.0f) ? ylo : yhi;
            float yf = (w11 >= 0.0f) ? yhi : ylo;

            float gxmin = __fadd_rn(__fadd_rn(__fmul_rn(xa, w00), __fmul_rn(ya, w01)), w02);
            float gxmax = __fadd_rn(__fadd_rn(__fmul_rn(xb, w00), __fmul_rn(yb, w01)), w02);
            float gymin = __fadd_rn(__fadd_rn(__fmul_rn(xc, w10), __fmul_rn(ye, w11)), w12);
            float gymax = __fadd_rn(__fadd_rn(__fmul_rn(xd, w10), __fmul_rn(yf, w11)), w12);

            cov = (gxmin >= -1.0f) && (gxmax < 1.0f) &&
                  (gymin >= -1.0f) && (gymax < 1.0f);
        }

        const unsigned long long m = __ballot(cov);
        const unsigned mg = (unsigned)(m >> (g * 8)) & 0xFFu;

        if (!gfound && mg != 0u) {
            const int jw = 31 - __clz(mg);      // highest covering stroke in chunk
            if (j == jw) { winner = true; wls = ls; }
            gfound = true;
        }

        if (__ballot(!gfound) == 0ull) break;
    }

    // ---- deferred epilogue: all winner lanes of the wave fetch together ----
    if (winner) {
        const int ls = wls;
        const float w00 = sp[0 * NL + ls];
        const float w01 = sp[1 * NL + ls];
        const float w02 = sp[2 * NL + ls];
        const float w10 = sp[3 * NL + ls];
        const float w11 = sp[4 * NL + ls];
        const float w12 = sp[5 * NL + ls];
        const float* __restrict__ br = brushes + sbo[ls];
        float gx = __fadd_rn(__fadd_rn(__fmul_rn(xs1, w00), __fmul_rn(ys1, w01)), w02);
        float gy = __fadd_rn(__fadd_rn(__fmul_rn(xs1, w10), __fmul_rn(ys1, w11)), w12);
        float xq = __fmul_rn(__fsub_rn(__fmul_rn(__fadd_rn(gx, 1.0f), 512.0f), 1.0f), 0.5f);
        float yq = __fmul_rn(__fsub_rn(__fmul_rn(__fadd_rn(gy, 1.0f), 512.0f), 1.0f), 0.5f);
        float xf = floorf(xq), yf = floorf(yq);
        int   x0i = (int)xf, y0i = (int)yf;
        float wx1 = __fsub_rn(xq, xf), wy1 = __fsub_rn(yq, yf);
        float wx0 = __fsub_rn(1.0f, wx1), wy0 = __fsub_rn(1.0f, wy1);
        float v00 = bil_tap(br, x0i,     y0i);
        float v10 = bil_tap(br, x0i + 1, y0i);
        float v01 = bil_tap(br, x0i,     y0i + 1);
        float v11 = bil_tap(br, x0i + 1, y0i + 1);
        float sv = __fadd_rn(__fadd_rn(__fadd_rn(
                       __fmul_rn(v00, __fmul_rn(wx0, wy0)),
                       __fmul_rn(v10, __fmul_rn(wx1, wy0))),
                       __fmul_rn(v01, __fmul_rn(wx0, wy1))),
                       __fmul_rn(v11, __fmul_rn(wx1, wy1)));
        out[img + 0 * (IH * IW) + pixo] = __fmul_rn(sv, sc[0 * NL + ls]);
        out[img + 1 * (IH * IW) + pixo] = __fmul_rn(sv, sc[1 * NL + ls]);
        out[img + 2 * (IH * IW) + pixo] = __fmul_rn(sv, sc[2 * NL + ls]);
    }

    if (!gfound && j == 0) {
        out[img + 0 * (IH * IW) + pixo] = 0.0f;
        out[img + 1 * (IH * IW) + pixo] = 0.0f;
        out[img + 2 * (IH * IW) + pixo] = 0.0f;
    }
}

extern "C" void kernel_launch(void* const* d_in, const int* in_sizes, int n_in,
                              void* d_out, int out_size, void* d_ws, size_t ws_size,
                              hipStream_t stream) {
    const float* params  = (const float*)d_in[0];   // (4,256,8) f32
    const float* brushes = (const float*)d_in[1];   // (2,1,512,512) f32
    float* out = (float*)d_out;                     // (4,3,128,128) f32
    (void)d_ws; (void)ws_size;                      // workspace not used

    // PROBE: two identical, idempotent launches. The stream serializes them,
    // so dur_us(this round) - 62.2us = one render duration.
    render_strokes<<<2048, 256, 0, stream>>>(brushes, params, out);
    render_strokes<<<2048, 256, 0, stream>>>(brushes, params, out);
}

// Round 5
// 62.225 us; speedup vs baseline: 1.1184x; 1.1184x over previous
//
#include <hip/hip_runtime.h>
#include <cmath>

#define IH 128
#define IW 128
#define NL 256          // strokes per batch image
#define NB 4            // batch
#define NS (NB * NL)    // 1024 strokes total
#define BSZ 512         // brush resolution

// d_ws layout: 10 planes of NS floats:
//   k=0..5  warp matrix rows (w00,w01,w02,w10,w11,w12)
//   k=6..8  colors (p5,p6,p7)
//   k=9     brush base offset as float (0.0f or 262144.0f, both exact)

// ---------------- pre-pass: per-stroke constants (exact ref ordering) ------
__global__ __launch_bounds__(256) void prep_strokes(
    const float* __restrict__ params,   // (4,256,8)
    float* __restrict__ wsf)
{
    const int s = blockIdx.x * 256 + threadIdx.x;   // 0..NS-1
    const float* __restrict__ p = params + (size_t)s * 8;
    float x0 = p[0], y0 = p[1], w = p[2], h = p[3], th = p[4];
    float ang   = __fmul_rn(3.14159265358979323846f, th);
    double ds, dc;
    sincos((double)ang, &ds, &dc);      // correctly-rounded f32 after cast
    float sin_t = (float)ds;
    float cos_t = (float)dc;
    float a_x = __fsub_rn(1.0f, __fmul_rn(2.0f, x0));
    float a_y = __fsub_rn(1.0f, __fmul_rn(2.0f, y0));
    // H==W==128 -> the H/W aspect factors are exactly 1.0
    wsf[0 * NS + s] = __fdiv_rn(cos_t, w);
    wsf[1 * NS + s] = __fdiv_rn(sin_t, w);
    wsf[2 * NS + s] = __fadd_rn(__fdiv_rn(__fmul_rn(a_x, cos_t), w),
                                __fdiv_rn(__fmul_rn(a_y, sin_t), w));
    wsf[3 * NS + s] = __fdiv_rn(-sin_t, h);
    wsf[4 * NS + s] = __fdiv_rn(cos_t, h);
    wsf[5 * NS + s] = __fsub_rn(__fdiv_rn(__fmul_rn(a_y, cos_t), h),
                                __fdiv_rn(__fmul_rn(a_x, sin_t), h));
    wsf[6 * NS + s] = p[5];
    wsf[7 * NS + s] = p[6];
    wsf[8 * NS + s] = p[7];
    wsf[9 * NS + s] = (h > w) ? 0.0f : (float)(BSZ * BSZ);  // idx=where(h>w,0,1)
}

// Bilinear tap exactly like reference: load clipped, zero if out of range.
__device__ __forceinline__ float bil_tap(const float* __restrict__ br, int ix, int iy) {
    int cx = min(max(ix, 0), BSZ - 1);
    int cy = min(max(iy, 0), BSZ - 1);
    float v = br[cy * BSZ + cx];
    bool ok = ((unsigned)ix < (unsigned)BSZ) && ((unsigned)iy < (unsigned)BSZ);
    return ok ? v : 0.0f;
}

// ------- render: pure-f32, no DP library code anywhere -------------------
// Round-5 change: ALL per-stroke constants come from the prep kernel via
// d_ws (10 coalesced plane loads -> LDS per block). This removes the
// 512x-redundant per-block DP sincos (524K library calls -> 1024), the
// dominant removable issue-work term in the warm-render 7.36us measured by
// the round-4 double-launch probe. Scan + deferred epilogue unchanged
// (bit-identical outputs to round 2).
__global__ __launch_bounds__(256) void render_strokes(
    const float* __restrict__ brushes,  // (2,1,512,512)
    const float* __restrict__ wsf,      // 10*NS floats (prep output)
    float* __restrict__ out)            // (4,3,128,128)
{
    __shared__ float sall[10 * NL];     // planes: 0..5 warp, 6..8 color, 9 bro

    const int t  = threadIdx.x;
    const int b  = blockIdx.x >> 9;     // 512 blocks per batch (32 px/block)
    const int sb = b * NL;

    // ---- stage all stroke constants (coalesced, L2/HBM once per block) ----
#pragma unroll
    for (int k = 0; k < 10; ++k) sall[k * NL + t] = wsf[k * NS + sb + t];
    __syncthreads();

    const float* __restrict__ sp = sall;            // 6 warp planes
    const float* __restrict__ sc = sall + 6 * NL;   // 3 color planes
    const float* __restrict__ sbo = sall + 9 * NL;  // brush-offset plane

    const int lane = t & 63;
    const int wid  = t >> 6;
    const int wave = blockIdx.x * 4 + wid;      // 0..8191
    const int g    = lane >> 3;                 // pixel group 0..7
    const int j    = lane & 7;                  // stroke sub-index 0..7
    const int P    = wave * 8 + g;              // global pixel id 0..65535
    const int pix  = P & 16383;
    const int py   = pix >> 7;
    const int px   = pix & 127;

    // per-pixel constants (uniform within each 8-lane group)
    float xs1, ys1, xlo, xhi, ylo, yhi;
    {
        float xs[3], ys[3];
#pragma unroll
        for (int d = 0; d < 3; ++d) {
            int qx = px + d - 1, qy = py + d - 1;
            xs[d] = (2.0f * (float)qx + 1.0f) / 128.0f - 1.0f;   // exact in f32
            ys[d] = (2.0f * (float)qy + 1.0f) / 128.0f - 1.0f;
        }
        xs1 = xs[1]; ys1 = ys[1];
        // inactive erosion taps duplicate the (always-active) center coord;
        // result stays monotone, so only the endpoints matter.
        xlo = (px - 1 >= 0) ? xs[0] : xs1;
        xhi = (px + 1 < IW) ? xs[2] : xs1;
        ylo = (py - 1 >= 0) ? ys[0] : ys1;
        yhi = (py + 1 < IH) ? ys[2] : ys1;
    }

    const size_t pixo = (size_t)py * IW + px;
    const size_t img  = (size_t)b * 3 * IH * IW;
    bool gfound = false;
    bool winner = false;
    int  wls    = 0;

    for (int c = 0; c < 32; ++c) {
        bool cov = false;
        int ls = 0;

        if (!gfound) {
            ls = (NL - 8 - 8 * c) + j;          // local stroke id, chunk from top
            const float w00 = sp[0 * NL + ls];
            const float w01 = sp[1 * NL + ls];
            const float w02 = sp[2 * NL + ls];
            const float w10 = sp[3 * NL + ls];
            const float w11 = sp[4 * NL + ls];
            const float w12 = sp[5 * NL + ls];

            // endpoint selection by coefficient sign (monotone xse/yse proof:
            // __fmul_rn by a constant is monotone, so the 3-tap min/max is
            // attained at an endpoint picked by sign(w); +-0 sign diffs
            // cannot flip the [-1,1) range tests)
            float xa = (w00 >= 0.0f) ? xlo : xhi;   // minimizes x*w00
            float xb = (w00 >= 0.0f) ? xhi : xlo;   // maximizes x*w00
            float ya = (w01 >= 0.0f) ? ylo : yhi;
            float yb = (w01 >= 0.0f) ? yhi : ylo;
            float xc = (w10 >= 0.0f) ? xlo : xhi;
            float xd = (w10 >= 0.0f) ? xhi : xlo;
            float ye = (w11 >= 0.0f) ? ylo : yhi;
            float yf = (w11 >= 0.0f) ? yhi : ylo;

            float gxmin = __fadd_rn(__fadd_rn(__fmul_rn(xa, w00), __fmul_rn(ya, w01)), w02);
            float gxmax = __fadd_rn(__fadd_rn(__fmul_rn(xb, w00), __fmul_rn(yb, w01)), w02);
            float gymin = __fadd_rn(__fadd_rn(__fmul_rn(xc, w10), __fmul_rn(ye, w11)), w12);
            float gymax = __fadd_rn(__fadd_rn(__fmul_rn(xd, w10), __fmul_rn(yf, w11)), w12);

            cov = (gxmin >= -1.0f) && (gxmax < 1.0f) &&
                  (gymin >= -1.0f) && (gymax < 1.0f);
        }

        const unsigned long long m = __ballot(cov);
        const unsigned mg = (unsigned)(m >> (g * 8)) & 0xFFu;

        if (!gfound && mg != 0u) {
            const int jw = 31 - __clz(mg);      // highest covering stroke in chunk
            if (j == jw) { winner = true; wls = ls; }
            gfound = true;
        }

        if (__ballot(!gfound) == 0ull) break;
    }

    // ---- deferred epilogue: all winner lanes of the wave fetch together ----
    if (winner) {
        const int ls = wls;
        const float w00 = sp[0 * NL + ls];
        const float w01 = sp[1 * NL + ls];
        const float w02 = sp[2 * NL + ls];
        const float w10 = sp[3 * NL + ls];
        const float w11 = sp[4 * NL + ls];
        const float w12 = sp[5 * NL + ls];
        const float* __restrict__ br = brushes + (int)sbo[ls];
        float gx = __fadd_rn(__fadd_rn(__fmul_rn(xs1, w00), __fmul_rn(ys1, w01)), w02);
        float gy = __fadd_rn(__fadd_rn(__fmul_rn(xs1, w10), __fmul_rn(ys1, w11)), w12);
        float xq = __fmul_rn(__fsub_rn(__fmul_rn(__fadd_rn(gx, 1.0f), 512.0f), 1.0f), 0.5f);
        float yq = __fmul_rn(__fsub_rn(__fmul_rn(__fadd_rn(gy, 1.0f), 512.0f), 1.0f), 0.5f);
        float xf = floorf(xq), yf = floorf(yq);
        int   x0i = (int)xf, y0i = (int)yf;
        float wx1 = __fsub_rn(xq, xf), wy1 = __fsub_rn(yq, yf);
        float wx0 = __fsub_rn(1.0f, wx1), wy0 = __fsub_rn(1.0f, wy1);
        float v00 = bil_tap(br, x0i,     y0i);
        float v10 = bil_tap(br, x0i + 1, y0i);
        float v01 = bil_tap(br, x0i,     y0i + 1);
        float v11 = bil_tap(br, x0i + 1, y0i + 1);
        float sv = __fadd_rn(__fadd_rn(__fadd_rn(
                       __fmul_rn(v00, __fmul_rn(wx0, wy0)),
                       __fmul_rn(v10, __fmul_rn(wx1, wy0))),
                       __fmul_rn(v01, __fmul_rn(wx0, wy1))),
                       __fmul_rn(v11, __fmul_rn(wx1, wy1)));
        out[img + 0 * (IH * IW) + pixo] = __fmul_rn(sv, sc[0 * NL + ls]);
        out[img + 1 * (IH * IW) + pixo] = __fmul_rn(sv, sc[1 * NL + ls]);
        out[img + 2 * (IH * IW) + pixo] = __fmul_rn(sv, sc[2 * NL + ls]);
    }

    if (!gfound && j == 0) {
        out[img + 0 * (IH * IW) + pixo] = 0.0f;
        out[img + 1 * (IH * IW) + pixo] = 0.0f;
        out[img + 2 * (IH * IW) + pixo] = 0.0f;
    }
}

extern "C" void kernel_launch(void* const* d_in, const int* in_sizes, int n_in,
                              void* d_out, int out_size, void* d_ws, size_t ws_size,
                              hipStream_t stream) {
    const float* params  = (const float*)d_in[0];   // (4,256,8) f32
    const float* brushes = (const float*)d_in[1];   // (2,1,512,512) f32
    float* out = (float*)d_out;                     // (4,3,128,128) f32
    float* wsf = (float*)d_ws;                      // 10*NS floats

    prep_strokes<<<NS / 256, 256, 0, stream>>>(params, wsf);
    // 65536 pixels / (8 pixels per wave * 4 waves per block) = 2048 blocks
    render_strokes<<<2048, 256, 0, stream>>>(brushes, wsf, out);
}